// Round 1
// baseline (641.075 us; speedup 1.0000x reference)
//
#include <hip/hip_runtime.h>

typedef __bf16 bf16x8 __attribute__((ext_vector_type(8)));
typedef float f32x4 __attribute__((ext_vector_type(4)));

// Problem constants
// x: [T=4][B=8][C1=64][H=128][W=128] fp32
// conv_w: [C2=128][C1=64][3][3] fp32, gamma/beta: [128]
// out: [T][B][C2=128][H][W] fp32 == [n=T*B][c2][h][w]
#define TBCHW_PLANE 8388608      // B*C1*H*W = 8*64*128*128 (elems per t)
#define NPIX 524288.0f           // N*H*W = 32*128*128
#define NBLK 4096                // stat partial columns = 512 blocks * 8 steps
#define SLOT_B 16640             // ring slot: 130 w_l positions * 64 c * 2 B

// ---------------- K0: weight repack to MFMA A-fragment order ----------------
// k ordering: k = tap*64 + c  (tap = kh*3+kw). Chunk kc (32 k's) => tap=kc>>1,
// c base=(kc&1)*32. Layout: wf[((kc*8+mtile)*64+lane)*8 + j], lane: m=lane&15,
// k_off=(lane>>4)*8+j  (A[m][k] per-lane fragment for mfma_f32_16x16x32_bf16).
__global__ __launch_bounds__(256) void prep_w(const float* __restrict__ w,
                                              __bf16* __restrict__ wf) {
    int o = blockIdx.x * 256 + threadIdx.x;
    if (o >= 73728) return;
    int j = o & 7;
    int lane = (o >> 3) & 63;
    int mtile = (o >> 9) & 7;
    int kc = o >> 12;
    int k = kc * 32 + (lane >> 4) * 8 + j;
    int c2 = mtile * 16 + (lane & 15);
    int tap = k >> 6, c = k & 63;
    int kh = tap / 3, kw = tap % 3;
    wf[o] = (__bf16)w[((c2 * 64 + c) * 3 + kh) * 3 + kw];
}

// ---------------- K1: LIF recurrence, fp32 exact, write s[n][h][w][c] bf16 ----
__device__ __forceinline__ float lif_step(float& mem, float sp, float xv) {
    // (mem - sp*0.5)*0.25 + xv : sp*0.5 and *0.25 are exact pow2 ops, so any
    // FMA contraction is bitwise-identical to the two-op IEEE sequence.
    mem = (mem - sp * 0.5f) * 0.25f + xv;
    return rintf(fminf(fmaxf(mem, 0.0f), 1.0f));   // round-half-even
}

__global__ __launch_bounds__(256) void lif_kernel(const float* __restrict__ x,
                                                  __bf16* __restrict__ s) {
    __shared__ __bf16 lds[2 * 128 * 72];  // [t2][w][c pad 72] (144B stride)
    int b = blockIdx.x >> 7, h = blockIdx.x & 127;
    int tid = threadIdx.x;

    float4 mem[8], sp[8];
#pragma unroll
    for (int i = 0; i < 8; ++i) { mem[i] = make_float4(0,0,0,0); sp[i] = make_float4(0,0,0,0); }

    for (int half = 0; half < 2; ++half) {
        if (half) __syncthreads();   // previous write-out done before LDS reuse
#pragma unroll
        for (int t2 = 0; t2 < 2; ++t2) {
            int t = half * 2 + t2;
#pragma unroll
            for (int i = 0; i < 8; ++i) {
                int p = tid + 256 * i;          // [0,2048): c=p>>5, w0=(p&31)*4
                int c = p >> 5, w0 = (p & 31) * 4;
                const float4 xv = *(const float4*)(x + (size_t)t * TBCHW_PLANE +
                                   (((size_t)b * 64 + c) * 128 + h) * 128 + w0);
                float s0 = lif_step(mem[i].x, sp[i].x, xv.x);
                float s1 = lif_step(mem[i].y, sp[i].y, xv.y);
                float s2 = lif_step(mem[i].z, sp[i].z, xv.z);
                float s3 = lif_step(mem[i].w, sp[i].w, xv.w);
                sp[i] = make_float4(s0, s1, s2, s3);
                __bf16* dst = &lds[(t2 * 128 + w0) * 72 + c];
                dst[0] = (__bf16)s0; dst[72] = (__bf16)s1;
                dst[144] = (__bf16)s2; dst[216] = (__bf16)s3;
            }
        }
        __syncthreads();
        // write-out: contiguous 16B chunks over [w][c] per (t,h)
#pragma unroll
        for (int i = 0; i < 8; ++i) {
            int u = tid + 256 * i;              // [0,2048)
            int t2 = u >> 10, inner = u & 1023;
            int w = inner >> 3, c8 = inner & 7;
            bf16x8 v = *(const bf16x8*)&lds[(t2 * 128 + w) * 72 + c8 * 8];
            int n = (half * 2 + t2) * 8 + b;
            *(bf16x8*)(s + (((size_t)n * 128 + h) * 128 + w) * 64 + c8 * 8) = v;
        }
    }
}

// ---------------- K2: h-marching implicit-GEMM conv ------------------------
// Grid 512 = 32 n * 16 h-chunks; each block marches 8 consecutive h rows.
// LDS: 4-row ring, each slot [w_l 0..129][c 64] bf16 (no pad; halo cols 0/129
// stay zero). Staging = global_load_lds dwordx4 with PRE-SWIZZLED global
// source (c8 ^= w_l&7) + linear LDS dest; K-loop ds_read applies the same
// XOR -> uniform 8-lanes-per-bank-group (the b128 minimum). One barrier per
// step; its implicit vmcnt(0) drain is the prefetch fence for the row staged
// at step start (consumed next step). kc=0..2 A-frags live in registers so
// early K-loop vmcnt waits don't force-drain the in-flight prefetch.
__device__ __forceinline__ void stage_row(const __bf16* __restrict__ s, int n, int hh,
                                          char* slot, int tid) {
    if (hh >= 0 && hh < 128) {
        const char* src = (const char*)s + (((size_t)n * 128 + hh) << 14);  // row base (16 KB)
#pragma unroll
        for (int i = 0; i < 4; ++i) {
            int g = i * 256 + tid;               // granule [0,1024): w=g>>3, pos=g&7
            int w = g >> 3;
            int sg = (w << 7) + (((g & 7) ^ ((w + 1) & 7)) << 4);  // inverse-swizzled source
            __builtin_amdgcn_global_load_lds(
                (const __attribute__((address_space(1))) unsigned int*)(src + sg),
                (__attribute__((address_space(3))) unsigned int*)(slot + 128 + g * 16),
                16, 0, 0);
        }
    } else {
        f32x4 z = {0.f, 0.f, 0.f, 0.f};
#pragma unroll
        for (int i = 0; i < 4; ++i) {
            int g = i * 256 + tid;
            *(f32x4*)(slot + 128 + g * 16) = z;
        }
    }
}

__global__ __launch_bounds__(256, 2) void conv_kernel(const __bf16* __restrict__ s,
                                                      const __bf16* __restrict__ wf,
                                                      float* __restrict__ out,
                                                      float* __restrict__ part) {
    __shared__ __align__(16) char ring[4 * SLOT_B];   // 66560 B
    __shared__ float2 P[2][256];                      // double-buffered stat scratch
    const int n  = blockIdx.x >> 4;
    const int h0 = (blockIdx.x & 15) << 3;
    const int tid = threadIdx.x;
    const int lane = tid & 63, wave = tid >> 6;
    const int wm = wave >> 1, wn = wave & 1;          // 2x2 wave grid, 64x64 each
    const int lm = lane & 15, q = lane >> 4;

    // zero halo columns w_l=0 and w_l=129 of all 4 slots (stay zero forever)
    if (tid < 64) {
        int slot = tid >> 4, col = (tid >> 3) & 1, g8 = tid & 7;
        f32x4 z = {0.f, 0.f, 0.f, 0.f};
        *(f32x4*)(ring + slot * SLOT_B + (col ? 129 * 128 : 0) + g8 * 16) = z;
    }

    // resident A fragments for kc = 0..2 (step-invariant; keeps early K-loop
    // vmcnt waits from draining the async row prefetch)
    bf16x8 ar0[4], ar1[4], ar2[4];
#pragma unroll
    for (int i = 0; i < 4; ++i) {
        ar0[i] = *(const bf16x8*)(wf + (((size_t)0 * 8 + wm * 4 + i) * 64 + lane) * 8);
        ar1[i] = *(const bf16x8*)(wf + (((size_t)1 * 8 + wm * 4 + i) * 64 + lane) * 8);
        ar2[i] = *(const bf16x8*)(wf + (((size_t)2 * 8 + wm * 4 + i) * 64 + lane) * 8);
    }

    // prologue: stage rows h0-1, h0, h0+1 into slots (h+4)&3
    stage_row(s, n, h0 - 1, ring + ((h0 + 3) & 3) * SLOT_B, tid);
    stage_row(s, n, h0,     ring + ((h0 + 0) & 3) * SLOT_B, tid);
    stage_row(s, n, h0 + 1, ring + ((h0 + 1) & 3) * SLOT_B, tid);
    __syncthreads();   // drains vmcnt+lgkm: staged rows + halo zeros visible

    const int wbyte = (wn * 64 + lm) * 128;   // per-lane w_l byte base (j adds 2048)

#pragma unroll 1
    for (int hs = 0; hs < 8; ++hs) {
        const int h = h0 + hs;
        // async prefetch of row h+2 into the free slot; lands before the
        // barrier at end of this step (consumed next step)
        if (hs < 7) stage_row(s, n, h + 2, ring + ((h + 2) & 3) * SLOT_B, tid);

        const char* rb0 = ring + ((h + 3) & 3) * SLOT_B;  // row h-1
        const char* rb1 = ring + ((h + 0) & 3) * SLOT_B;  // row h
        const char* rb2 = ring + ((h + 1) & 3) * SLOT_B;  // row h+1

        f32x4 acc[4][4];
#pragma unroll
        for (int i = 0; i < 4; ++i)
#pragma unroll
            for (int j = 0; j < 4; ++j)
#pragma unroll
                for (int e = 0; e < 4; ++e) acc[i][j][e] = 0.0f;

#pragma unroll
        for (int kc = 0; kc < 18; ++kc) {
            const int tap = kc >> 1;
            const int kh = tap / 3, kw = tap - kh * 3;   // compile-time (unrolled)
            const int c8b = (kc & 1) * 4;
            const char* rb = (kh == 0) ? rb0 : (kh == 1) ? rb1 : rb2;
            // swizzle is j-independent: (w_l & 7) == (lm + kw) & 7
            const int off = kw * 128 + ((((c8b + q) ^ ((lm + kw) & 7))) << 4);
            bf16x8 av[4], bv[4];
#pragma unroll
            for (int i = 0; i < 4; ++i)
                av[i] = (kc == 0) ? ar0[i] : (kc == 1) ? ar1[i] : (kc == 2) ? ar2[i]
                      : *(const bf16x8*)(wf + (((size_t)kc * 8 + wm * 4 + i) * 64 + lane) * 8);
#pragma unroll
            for (int j = 0; j < 4; ++j)
                bv[j] = *(const bf16x8*)(rb + wbyte + j * 2048 + off);
#pragma unroll
            for (int i = 0; i < 4; ++i)
#pragma unroll
                for (int j = 0; j < 4; ++j)
                    acc[i][j] = __builtin_amdgcn_mfma_f32_16x16x32_bf16(av[i], bv[j], acc[i][j], 0, 0, 0);
        }

        // epilogue: D[m = q*4+r][nn = lane&15]; store fp32 + per-channel partials
#pragma unroll
        for (int i = 0; i < 4; ++i) {
#pragma unroll
            for (int r = 0; r < 4; ++r) {
                int c2 = wm * 64 + i * 16 + q * 4 + r;
                size_t ob = ((size_t)(n * 128 + c2) * 128 + h) * 128 + wn * 64 + lm;
                float sum = 0.0f, ssq = 0.0f;
#pragma unroll
                for (int j = 0; j < 4; ++j) {
                    float v = acc[i][j][r];
                    out[ob + j * 16] = v;
                    sum += v; ssq += v * v;
                }
                // reduce over the 16 lanes sharing q (shifts stay within group)
#pragma unroll
                for (int d = 8; d > 0; d >>= 1) {
                    sum += __shfl_down(sum, d);
                    ssq += __shfl_down(ssq, d);
                }
                if (lm == 0)
                    P[hs & 1][wave * 64 + i * 16 + q * 4 + r] = make_float2(sum, ssq);
            }
        }
        __syncthreads();   // ONE barrier/step: P visible + prefetch vmcnt drained
        {
            int stat = tid >> 7, c2x = tid & 127;
            int wp = c2x >> 6, idx = c2x & 63;
            float2 a2 = P[hs & 1][(wp * 2) * 64 + idx];
            float2 b2 = P[hs & 1][(wp * 2 + 1) * 64 + idx];
            float val = stat ? (a2.y + b2.y) : (a2.x + b2.x);
            part[(size_t)tid * NBLK + (blockIdx.x << 3) + hs] = val;
        }
        // no second barrier: next step writes P[(hs+1)&1]; a thread only
        // reaches the NEXT P-write for this buffer after the next barrier,
        // by which point every thread has finished this combine.
    }
}

// ---------------- K2b: reduce partials + finalize scale/shift ---------------
// 128 blocks, block c reduces part rows c (sum) and 128+c (ssq), each NBLK long.
__global__ __launch_bounds__(256) void reduce_stats(const float* __restrict__ part,
                                                    const float* __restrict__ gamma,
                                                    const float* __restrict__ beta,
                                                    float* __restrict__ ss) {
    int c = blockIdx.x;
    int tid = threadIdx.x;
    const float* ps = part + (size_t)c * NBLK;
    const float* pq = part + (size_t)(128 + c) * NBLK;
    float sum = 0.0f, ssq = 0.0f;
    for (int i = tid; i < NBLK; i += 256) { sum += ps[i]; ssq += pq[i]; }
#pragma unroll
    for (int d = 32; d > 0; d >>= 1) {
        sum += __shfl_down(sum, d);
        ssq += __shfl_down(ssq, d);
    }
    __shared__ float2 wred[4];
    if ((tid & 63) == 0) wred[tid >> 6] = make_float2(sum, ssq);
    __syncthreads();
    if (tid == 0) {
        float S = 0.0f, Q = 0.0f;
#pragma unroll
        for (int w2 = 0; w2 < 4; ++w2) { S += wred[w2].x; Q += wred[w2].y; }
        const float inv = 1.0f / NPIX;
        float mean = S * inv;
        float var = Q * inv - mean * mean;
        float sc = gamma[c] * rsqrtf(var + 1e-5f);
        ss[c] = sc;
        ss[128 + c] = beta[c] - mean * sc;
    }
}

// ---------------- K3: in-place BN apply (float4) ----------------------------
__global__ __launch_bounds__(256) void bn_apply(float* __restrict__ out,
                                                const float* __restrict__ ss) {
    size_t i4 = (size_t)blockIdx.x * 256 + threadIdx.x;   // 16777216 float4s
    int c2 = (int)((i4 >> 12) & 127);
    float sc = ss[c2], sh = ss[128 + c2];
    float4* p = (float4*)out + i4;
    float4 v = *p;
    v.x = v.x * sc + sh; v.y = v.y * sc + sh;
    v.z = v.z * sc + sh; v.w = v.w * sc + sh;
    *p = v;
}

extern "C" void kernel_launch(void* const* d_in, const int* in_sizes, int n_in,
                              void* d_out, int out_size, void* d_ws, size_t ws_size,
                              hipStream_t stream) {
    const float* x     = (const float*)d_in[0];
    const float* cw    = (const float*)d_in[1];
    const float* gamma = (const float*)d_in[2];
    const float* beta  = (const float*)d_in[3];
    float* out = (float*)d_out;

    char* ws = (char*)d_ws;
    __bf16* s     = (__bf16*)ws;                           // 67108864 B
    __bf16* wfrag = (__bf16*)(ws + 67108864);              // 147456 B
    float*  part  = (float*)(ws + 67108864 + 147456);      // 256*NBLK*4 = 4 MB
    float*  ss    = part + 256 * NBLK;                     // 256 floats

    prep_w      <<<288,   256, 0, stream>>>(cw, wfrag);
    lif_kernel  <<<1024,  256, 0, stream>>>(x, s);
    conv_kernel <<<512,   256, 0, stream>>>(s, wfrag, out, part);
    reduce_stats<<<128,   256, 0, stream>>>(part, gamma, beta, ss);
    bn_apply    <<<65536, 256, 0, stream>>>(out, ss);
}

// Round 2
// 541.281 us; speedup vs baseline: 1.1844x; 1.1844x over previous
//
#include <hip/hip_runtime.h>

typedef __bf16 bf16x8 __attribute__((ext_vector_type(8)));
typedef float f32x4 __attribute__((ext_vector_type(4)));

// Problem constants
// x: [T=4][B=8][C1=64][H=128][W=128] fp32
// conv_w: [C2=128][C1=64][3][3] fp32, gamma/beta: [128]
// out: [T][B][C2=128][H][W] fp32 == [n=T*B][c2][h][w]
#define TBCHW_PLANE 8388608      // B*C1*H*W = 8*64*128*128 (elems per t)
#define NPIX 524288.0f           // N*H*W = 32*128*128
#define NBLK 4096                // conv grid size (one block per (n,h))
#define SLOT_B 16640             // LDS row slot: 130 w_l positions * 64 c * 2 B

// ---------------- K0: weight repack to MFMA A-fragment order ----------------
// k ordering: k = tap*64 + c  (tap = kh*3+kw). Chunk kc (32 k's) => tap=kc>>1,
// c base=(kc&1)*32. Layout: wf[((kc*8+mtile)*64+lane)*8 + j], lane: m=lane&15,
// k_off=(lane>>4)*8+j  (A[m][k] per-lane fragment for mfma_f32_16x16x32_bf16).
__global__ __launch_bounds__(256) void prep_w(const float* __restrict__ w,
                                              __bf16* __restrict__ wf) {
    int o = blockIdx.x * 256 + threadIdx.x;
    if (o >= 73728) return;
    int j = o & 7;
    int lane = (o >> 3) & 63;
    int mtile = (o >> 9) & 7;
    int kc = o >> 12;
    int k = kc * 32 + (lane >> 4) * 8 + j;
    int c2 = mtile * 16 + (lane & 15);
    int tap = k >> 6, c = k & 63;
    int kh = tap / 3, kw = tap % 3;
    wf[o] = (__bf16)w[((c2 * 64 + c) * 3 + kh) * 3 + kw];
}

// ---------------- K1: LIF recurrence, fp32 exact, write s[n][h][w][c] bf16 ----
__device__ __forceinline__ float lif_step(float& mem, float sp, float xv) {
    // (mem - sp*0.5)*0.25 + xv : sp*0.5 and *0.25 are exact pow2 ops, so any
    // FMA contraction is bitwise-identical to the two-op IEEE sequence.
    mem = (mem - sp * 0.5f) * 0.25f + xv;
    return rintf(fminf(fmaxf(mem, 0.0f), 1.0f));   // round-half-even
}

__global__ __launch_bounds__(256) void lif_kernel(const float* __restrict__ x,
                                                  __bf16* __restrict__ s) {
    __shared__ __bf16 lds[2 * 128 * 72];  // [t2][w][c pad 72] (144B stride)
    int b = blockIdx.x >> 7, h = blockIdx.x & 127;
    int tid = threadIdx.x;

    float4 mem[8], sp[8];
#pragma unroll
    for (int i = 0; i < 8; ++i) { mem[i] = make_float4(0,0,0,0); sp[i] = make_float4(0,0,0,0); }

    for (int half = 0; half < 2; ++half) {
        if (half) __syncthreads();   // previous write-out done before LDS reuse
#pragma unroll
        for (int t2 = 0; t2 < 2; ++t2) {
            int t = half * 2 + t2;
#pragma unroll
            for (int i = 0; i < 8; ++i) {
                int p = tid + 256 * i;          // [0,2048): c=p>>5, w0=(p&31)*4
                int c = p >> 5, w0 = (p & 31) * 4;
                const float4 xv = *(const float4*)(x + (size_t)t * TBCHW_PLANE +
                                   (((size_t)b * 64 + c) * 128 + h) * 128 + w0);
                float s0 = lif_step(mem[i].x, sp[i].x, xv.x);
                float s1 = lif_step(mem[i].y, sp[i].y, xv.y);
                float s2 = lif_step(mem[i].z, sp[i].z, xv.z);
                float s3 = lif_step(mem[i].w, sp[i].w, xv.w);
                sp[i] = make_float4(s0, s1, s2, s3);
                __bf16* dst = &lds[(t2 * 128 + w0) * 72 + c];
                dst[0] = (__bf16)s0; dst[72] = (__bf16)s1;
                dst[144] = (__bf16)s2; dst[216] = (__bf16)s3;
            }
        }
        __syncthreads();
        // write-out: contiguous 16B chunks over [w][c] per (t,h)
#pragma unroll
        for (int i = 0; i < 8; ++i) {
            int u = tid + 256 * i;              // [0,2048)
            int t2 = u >> 10, inner = u & 1023;
            int w = inner >> 3, c8 = inner & 7;
            bf16x8 v = *(const bf16x8*)&lds[(t2 * 128 + w) * 72 + c8 * 8];
            int n = (half * 2 + t2) * 8 + b;
            *(bf16x8*)(s + (((size_t)n * 128 + h) * 128 + w) * 64 + c8 * 8) = v;
        }
    }
}

// ---------------- K2: implicit-GEMM conv (4096 blocks, swizzled LDS) --------
// Block = one (n, h): full C2=128 x W=128 tile. Proven R0 concurrency pattern
// (consecutive blocks = consecutive h; part columns written by concurrent
// blocks -> L2-friendly). R1's verified-working pieces transplanted:
//  - pad-free [w_l 0..129][c 64] rows, XOR-swizzle (c8 ^= w_l&7): bank
//    conflicts 4.8M -> 65K measured in R1.
//  - staging via global_load_lds dwordx4 with PRE-SWIZZLED global source +
//    linear LDS dest (rule: swizzle both sides or neither).
//  - LDS 56160 -> 49920 B => 3 blocks/CU (12 waves/CU) for wf-load latency
//    cover.
//  - XCD-chunked bid swizzle: adjacent-h blocks (sharing 2/3 staged rows)
//    land on the same XCD's L2.
__global__ __launch_bounds__(256, 3) void conv_kernel(const __bf16* __restrict__ s,
                                                      const __bf16* __restrict__ wf,
                                                      float* __restrict__ out,
                                                      float* __restrict__ part) {
    __shared__ __align__(16) char sb3[3 * SLOT_B];   // 49920 B
    const int p = blockIdx.x;
    const int bid = (p & 7) * 512 + (p >> 3);        // bijective XCD-chunk map
    const int n = bid >> 7, h = bid & 127;
    const int tid = threadIdx.x;

    // stage rows h-1..h+1 into slots kh=0..2 (each 128w x 64c bf16, 16 KB)
#pragma unroll
    for (int r = 0; r < 3; ++r) {
        int hh = h + r - 1;
        char* slot = sb3 + r * SLOT_B;
        if (hh >= 0 && hh < 128) {
            const char* src = (const char*)s + (((size_t)n * 128 + hh) << 14);
#pragma unroll
            for (int i = 0; i < 4; ++i) {
                int g = i * 256 + tid;               // granule [0,1024): w=g>>3
                int w = g >> 3;
                int sg = (w << 7) + (((g & 7) ^ ((w + 1) & 7)) << 4);  // inv-swizzled src
                __builtin_amdgcn_global_load_lds(
                    (const __attribute__((address_space(1))) unsigned int*)(src + sg),
                    (__attribute__((address_space(3))) unsigned int*)(slot + 128 + g * 16),
                    16, 0, 0);
            }
        } else {
            f32x4 z = {0.f, 0.f, 0.f, 0.f};
#pragma unroll
            for (int i = 0; i < 4; ++i)
                *(f32x4*)(slot + 128 + (i * 256 + tid) * 16) = z;
        }
    }
    if (tid < 48) {   // zero halo columns w_l=0 and w_l=129 of the 3 slots
        int r = tid / 16, q16 = tid % 16;
        int col = q16 & 1, g8 = q16 >> 1;
        f32x4 z = {0.f, 0.f, 0.f, 0.f};
        *(f32x4*)(sb3 + r * SLOT_B + (col ? 129 * 128 : 0) + g8 * 16) = z;
    }
    __syncthreads();   // drains vmcnt (gload_lds) + lgkm (halo zeros)

    const int lane = tid & 63, wave = tid >> 6;
    const int wm = wave >> 1, wn = wave & 1;    // 2x2 wave grid, 64x64 each
    const int lm = lane & 15, q = lane >> 4;
    const int wbyte = (wn * 64 + lm) * 128;     // w_l byte base (j adds 2048)

    f32x4 acc[4][4];
#pragma unroll
    for (int i = 0; i < 4; ++i)
#pragma unroll
        for (int j = 0; j < 4; ++j)
#pragma unroll
            for (int e = 0; e < 4; ++e) acc[i][j][e] = 0.0f;

#pragma unroll
    for (int kc = 0; kc < 18; ++kc) {
        const int tap = kc >> 1;
        const int kh = tap / 3, kw = tap - kh * 3;   // compile-time (unrolled)
        const int c8b = (kc & 1) * 4;
        const char* rb = sb3 + kh * SLOT_B;
        // swizzle is j/wn-independent: (w_l & 7) == (lm + kw) & 7
        const int off = kw * 128 + (((c8b + q) ^ ((lm + kw) & 7)) << 4);
        bf16x8 a[4], bb[4];
#pragma unroll
        for (int i = 0; i < 4; ++i)
            a[i] = *(const bf16x8*)(wf + (((size_t)kc * 8 + wm * 4 + i) * 64 + lane) * 8);
#pragma unroll
        for (int j = 0; j < 4; ++j)
            bb[j] = *(const bf16x8*)(rb + wbyte + j * 2048 + off);
#pragma unroll
        for (int i = 0; i < 4; ++i)
#pragma unroll
            for (int j = 0; j < 4; ++j)
                acc[i][j] = __builtin_amdgcn_mfma_f32_16x16x32_bf16(a[i], bb[j], acc[i][j], 0, 0, 0);
    }

    __syncthreads();                       // done reading sb3; reuse as float2 P
    float2* P = (float2*)sb3;              // P[wave*64 + idx], idx = i*16+q*4+r

    // epilogue: D[m = q*4+r][nn = lane&15]; store fp32 + per-channel partials
#pragma unroll
    for (int i = 0; i < 4; ++i) {
#pragma unroll
        for (int r = 0; r < 4; ++r) {
            int c2 = wm * 64 + i * 16 + q * 4 + r;
            size_t ob = ((size_t)(n * 128 + c2) * 128 + h) * 128 + wn * 64 + lm;
            float sum = 0.0f, ssq = 0.0f;
#pragma unroll
            for (int j = 0; j < 4; ++j) {
                float v = acc[i][j][r];
                out[ob + j * 16] = v;
                sum += v; ssq += v * v;
            }
            // reduce over the 16 lanes sharing q (shifts stay within group)
#pragma unroll
            for (int d = 8; d > 0; d >>= 1) {
                sum += __shfl_down(sum, d);
                ssq += __shfl_down(ssq, d);
            }
            if (lm == 0) {
                // each P slot written exactly once per block (no atomics)
                P[wave * 64 + i * 16 + q * 4 + r] = make_float2(sum, ssq);
            }
        }
    }
    __syncthreads();
    // combine the wave pair sharing wm, write one partial row element
    {
        int stat = tid >> 7, c2x = tid & 127;      // row = stat*128+c2x == tid
        int wp = c2x >> 6, idx = c2x & 63;
        float2 a2 = P[(wp * 2) * 64 + idx];
        float2 b2 = P[(wp * 2 + 1) * 64 + idx];
        float val = stat ? (a2.y + b2.y) : (a2.x + b2.x);
        part[(size_t)tid * NBLK + bid] = val;
    }
}

// ---------------- K2b: reduce partials + finalize scale/shift ---------------
// 128 blocks, block c reduces part rows c (sum) and 128+c (ssq), each NBLK long.
__global__ __launch_bounds__(256) void reduce_stats(const float* __restrict__ part,
                                                    const float* __restrict__ gamma,
                                                    const float* __restrict__ beta,
                                                    float* __restrict__ ss) {
    int c = blockIdx.x;
    int tid = threadIdx.x;
    const float* ps = part + (size_t)c * NBLK;
    const float* pq = part + (size_t)(128 + c) * NBLK;
    float sum = 0.0f, ssq = 0.0f;
    for (int i = tid; i < NBLK; i += 256) { sum += ps[i]; ssq += pq[i]; }
#pragma unroll
    for (int d = 32; d > 0; d >>= 1) {
        sum += __shfl_down(sum, d);
        ssq += __shfl_down(ssq, d);
    }
    __shared__ float2 wred[4];
    if ((tid & 63) == 0) wred[tid >> 6] = make_float2(sum, ssq);
    __syncthreads();
    if (tid == 0) {
        float S = 0.0f, Q = 0.0f;
#pragma unroll
        for (int w2 = 0; w2 < 4; ++w2) { S += wred[w2].x; Q += wred[w2].y; }
        const float inv = 1.0f / NPIX;
        float mean = S * inv;
        float var = Q * inv - mean * mean;
        float sc = gamma[c] * rsqrtf(var + 1e-5f);
        ss[c] = sc;
        ss[128 + c] = beta[c] - mean * sc;
    }
}

// ---------------- K3: in-place BN apply (float4, grid-stride) ---------------
__global__ __launch_bounds__(256) void bn_apply(float* __restrict__ out,
                                                const float* __restrict__ ss) {
    const size_t stride = (size_t)2048 * 256;
    for (size_t i4 = (size_t)blockIdx.x * 256 + threadIdx.x; i4 < 16777216; i4 += stride) {
        int c2 = (int)((i4 >> 12) & 127);      // uniform within a block-iteration
        float sc = ss[c2], sh = ss[128 + c2];
        float4* p = (float4*)out + i4;
        float4 v = *p;
        v.x = v.x * sc + sh; v.y = v.y * sc + sh;
        v.z = v.z * sc + sh; v.w = v.w * sc + sh;
        *p = v;
    }
}

extern "C" void kernel_launch(void* const* d_in, const int* in_sizes, int n_in,
                              void* d_out, int out_size, void* d_ws, size_t ws_size,
                              hipStream_t stream) {
    const float* x     = (const float*)d_in[0];
    const float* cw    = (const float*)d_in[1];
    const float* gamma = (const float*)d_in[2];
    const float* beta  = (const float*)d_in[3];
    float* out = (float*)d_out;

    char* ws = (char*)d_ws;
    __bf16* s     = (__bf16*)ws;                           // 67108864 B
    __bf16* wfrag = (__bf16*)(ws + 67108864);              // 147456 B
    float*  part  = (float*)(ws + 67108864 + 147456);      // 256*NBLK*4 = 4 MB
    float*  ss    = part + 256 * NBLK;                     // 256 floats

    prep_w      <<<288,   256, 0, stream>>>(cw, wfrag);
    lif_kernel  <<<1024,  256, 0, stream>>>(x, s);
    conv_kernel <<<NBLK,  256, 0, stream>>>(s, wfrag, out, part);
    reduce_stats<<<128,   256, 0, stream>>>(part, gamma, beta, ss);
    bn_apply    <<<2048,  256, 0, stream>>>(out, ss);
}

// Round 3
// 538.503 us; speedup vs baseline: 1.1905x; 1.0052x over previous
//
#include <hip/hip_runtime.h>

typedef __bf16 bf16x8 __attribute__((ext_vector_type(8)));
typedef float f32x4 __attribute__((ext_vector_type(4)));

// Problem constants
// x: [T=4][B=8][C1=64][H=128][W=128] fp32
// conv_w: [C2=128][C1=64][3][3] fp32, gamma/beta: [128]
// out: [T][B][C2=128][H][W] fp32 == [n=T*B][c2][h][w]
#define TBCHW_PLANE 8388608      // B*C1*H*W = 8*64*128*128 (elems per t)
#define NPIX 524288.0f           // N*H*W = 32*128*128
#define NBLK 4096                // conv grid size (one block per (n,h))
#define SLOT_B 16640             // LDS row slot: 130 w_l positions * 64 c * 2 B

// ---------------- K0: weight repack to MFMA A-fragment order ----------------
// k ordering: k = tap*64 + c  (tap = kh*3+kw). Chunk kc (32 k's) => tap=kc>>1,
// c base=(kc&1)*32. Layout: wf[((kc*8+mtile)*64+lane)*8 + j], lane: m=lane&15,
// k_off=(lane>>4)*8+j  (A[m][k] per-lane fragment for mfma_f32_16x16x32_bf16).
__global__ __launch_bounds__(256) void prep_w(const float* __restrict__ w,
                                              __bf16* __restrict__ wf) {
    int o = blockIdx.x * 256 + threadIdx.x;
    if (o >= 73728) return;
    int j = o & 7;
    int lane = (o >> 3) & 63;
    int mtile = (o >> 9) & 7;
    int kc = o >> 12;
    int k = kc * 32 + (lane >> 4) * 8 + j;
    int c2 = mtile * 16 + (lane & 15);
    int tap = k >> 6, c = k & 63;
    int kh = tap / 3, kw = tap % 3;
    wf[o] = (__bf16)w[((c2 * 64 + c) * 3 + kh) * 3 + kw];
}

// ---------------- K1: LIF recurrence, fp32 exact, write s[n][h][w][c] bf16 ----
// LDS transpose layout: row stride 72 elems (144 B, keeps 16B-aligned vector
// reads), c-position XOR-swizzled by ((w>>2)&7)<<3.  Un-swizzled, the store
// lane-stride is 144 words = 0 mod 32 -> ALL lanes on bank 0 (32-way conflict
// on every scalar store).  The XOR spreads the 32 lanes of a half-wave over
// 8 bank groups (4-way, ~1.58x = near-free per G4).  Read side: the XOR only
// permutes aligned 8-c blocks within a row, so bf16x8 reads stay contiguous
// and 16B-aligned.  Global layout of s is unchanged.
__device__ __forceinline__ float lif_step(float& mem, float sp, float xv) {
    // (mem - sp*0.5)*0.25 + xv : sp*0.5 and *0.25 are exact pow2 ops, so any
    // FMA contraction is bitwise-identical to the two-op IEEE sequence.
    mem = (mem - sp * 0.5f) * 0.25f + xv;
    return rintf(fminf(fmaxf(mem, 0.0f), 1.0f));   // round-half-even
}

__global__ __launch_bounds__(256) void lif_kernel(const float* __restrict__ x,
                                                  __bf16* __restrict__ s) {
    __shared__ __bf16 lds[2 * 128 * 72];  // [t2][w][c' 72] (144B row stride)
    int b = blockIdx.x >> 7, h = blockIdx.x & 127;
    int tid = threadIdx.x;

    float4 mem[8], sp[8];
#pragma unroll
    for (int i = 0; i < 8; ++i) { mem[i] = make_float4(0,0,0,0); sp[i] = make_float4(0,0,0,0); }

    for (int half = 0; half < 2; ++half) {
        if (half) __syncthreads();   // previous write-out done before LDS reuse
#pragma unroll
        for (int t2 = 0; t2 < 2; ++t2) {
            int t = half * 2 + t2;
#pragma unroll
            for (int i = 0; i < 8; ++i) {
                int p = tid + 256 * i;          // [0,2048): c=p>>5, w0=(p&31)*4
                int c = p >> 5, w0 = (p & 31) * 4;
                const float4 xv = *(const float4*)(x + (size_t)t * TBCHW_PLANE +
                                   (((size_t)b * 64 + c) * 128 + h) * 128 + w0);
                float s0 = lif_step(mem[i].x, sp[i].x, xv.x);
                float s1 = lif_step(mem[i].y, sp[i].y, xv.y);
                float s2 = lif_step(mem[i].z, sp[i].z, xv.z);
                float s3 = lif_step(mem[i].w, sp[i].w, xv.w);
                sp[i] = make_float4(s0, s1, s2, s3);
                // swizzled c position; (w0+k)>>2 == w0>>2 for k<4, so one base
                int cs = c ^ ((p & 7) << 3);    // (w0>>2)&7 == p&7
                __bf16* dst = &lds[(t2 * 128 + w0) * 72 + cs];
                dst[0] = (__bf16)s0; dst[72] = (__bf16)s1;
                dst[144] = (__bf16)s2; dst[216] = (__bf16)s3;
            }
        }
        __syncthreads();
        // write-out: contiguous 16B chunks over [w][c] per (t,h)
#pragma unroll
        for (int i = 0; i < 8; ++i) {
            int u = tid + 256 * i;              // [0,2048)
            int t2 = u >> 10, inner = u & 1023;
            int w = inner >> 3, c8 = inner & 7;
            int c8s = c8 ^ ((w >> 2) & 7);      // undo the store swizzle
            bf16x8 v = *(const bf16x8*)&lds[(t2 * 128 + w) * 72 + c8s * 8];
            int n = (half * 2 + t2) * 8 + b;
            *(bf16x8*)(s + (((size_t)n * 128 + h) * 128 + w) * 64 + c8 * 8) = v;
        }
    }
}

// ---------------- K2: implicit-GEMM conv (4096 blocks, swizzled LDS) --------
// Block = one (n, h): full C2=128 x W=128 tile. R2-verified structure:
//  - pad-free [w_l 0..129][c 64] rows, XOR-swizzle (c8 ^= w_l&7), staged via
//    global_load_lds dwordx4 with pre-swizzled global source (conflicts
//    4.8M -> 65K measured).
//  - 49920 B LDS => 3 blocks/CU (12 waves/CU).
//  - XCD-chunked bid swizzle: adjacent-h blocks (sharing 2/3 staged rows)
//    land on the same XCD's L2.
// NEW (R3): 1-deep software pipeline on the wf A-fragments — load kc+1's
// fragments before kc's MFMAs so the ~200cy L2 latency hides under compute
// instead of serializing each kc.
__global__ __launch_bounds__(256, 3) void conv_kernel(const __bf16* __restrict__ s,
                                                      const __bf16* __restrict__ wf,
                                                      float* __restrict__ out,
                                                      float* __restrict__ part) {
    __shared__ __align__(16) char sb3[3 * SLOT_B];   // 49920 B
    const int p = blockIdx.x;
    const int bid = (p & 7) * 512 + (p >> 3);        // bijective XCD-chunk map
    const int n = bid >> 7, h = bid & 127;
    const int tid = threadIdx.x;

    // stage rows h-1..h+1 into slots kh=0..2 (each 128w x 64c bf16, 16 KB)
#pragma unroll
    for (int r = 0; r < 3; ++r) {
        int hh = h + r - 1;
        char* slot = sb3 + r * SLOT_B;
        if (hh >= 0 && hh < 128) {
            const char* src = (const char*)s + (((size_t)n * 128 + hh) << 14);
#pragma unroll
            for (int i = 0; i < 4; ++i) {
                int g = i * 256 + tid;               // granule [0,1024): w=g>>3
                int w = g >> 3;
                int sg = (w << 7) + (((g & 7) ^ ((w + 1) & 7)) << 4);  // inv-swizzled src
                __builtin_amdgcn_global_load_lds(
                    (const __attribute__((address_space(1))) unsigned int*)(src + sg),
                    (__attribute__((address_space(3))) unsigned int*)(slot + 128 + g * 16),
                    16, 0, 0);
            }
        } else {
            f32x4 z = {0.f, 0.f, 0.f, 0.f};
#pragma unroll
            for (int i = 0; i < 4; ++i)
                *(f32x4*)(slot + 128 + (i * 256 + tid) * 16) = z;
        }
    }
    if (tid < 48) {   // zero halo columns w_l=0 and w_l=129 of the 3 slots
        int r = tid / 16, q16 = tid % 16;
        int col = q16 & 1, g8 = q16 >> 1;
        f32x4 z = {0.f, 0.f, 0.f, 0.f};
        *(f32x4*)(sb3 + r * SLOT_B + (col ? 129 * 128 : 0) + g8 * 16) = z;
    }

    const int lane = tid & 63, wave = tid >> 6;
    const int wm = wave >> 1, wn = wave & 1;    // 2x2 wave grid, 64x64 each
    const int lm = lane & 15, q = lane >> 4;
    const int wbyte = (wn * 64 + lm) * 128;     // w_l byte base (j adds 2048)

    // preload kc=0 A-fragments while the staging loads are in flight
    bf16x8 aC[4], aN[4];
#pragma unroll
    for (int i = 0; i < 4; ++i)
        aC[i] = *(const bf16x8*)(wf + (((size_t)wm * 4 + i) * 64 + lane) * 8);

    __syncthreads();   // drains vmcnt (gload_lds) + lgkm (halo zeros)

    f32x4 acc[4][4];
#pragma unroll
    for (int i = 0; i < 4; ++i)
#pragma unroll
        for (int j = 0; j < 4; ++j)
#pragma unroll
            for (int e = 0; e < 4; ++e) acc[i][j][e] = 0.0f;

#pragma unroll
    for (int kc = 0; kc < 18; ++kc) {
        const int tap = kc >> 1;
        const int kh = tap / 3, kw = tap - kh * 3;   // compile-time (unrolled)
        const int c8b = (kc & 1) * 4;
        const char* rb = sb3 + kh * SLOT_B;
        // swizzle is j/wn-independent: (w_l & 7) == (lm + kw) & 7
        const int off = kw * 128 + (((c8b + q) ^ ((lm + kw) & 7)) << 4);
        // software-pipelined A: issue kc+1's loads before kc's MFMAs
        if (kc < 17) {
#pragma unroll
            for (int i = 0; i < 4; ++i)
                aN[i] = *(const bf16x8*)(wf + (((size_t)(kc + 1) * 8 + wm * 4 + i) * 64 + lane) * 8);
        }
        bf16x8 bb[4];
#pragma unroll
        for (int j = 0; j < 4; ++j)
            bb[j] = *(const bf16x8*)(rb + wbyte + j * 2048 + off);
#pragma unroll
        for (int i = 0; i < 4; ++i)
#pragma unroll
            for (int j = 0; j < 4; ++j)
                acc[i][j] = __builtin_amdgcn_mfma_f32_16x16x32_bf16(aC[i], bb[j], acc[i][j], 0, 0, 0);
#pragma unroll
        for (int i = 0; i < 4; ++i) aC[i] = aN[i];   // renamed away by unroll
    }

    __syncthreads();                       // done reading sb3; reuse as float2 P
    float2* P = (float2*)sb3;              // P[wave*64 + idx], idx = i*16+q*4+r

    // epilogue: D[m = q*4+r][nn = lane&15]; store fp32 + per-channel partials
#pragma unroll
    for (int i = 0; i < 4; ++i) {
#pragma unroll
        for (int r = 0; r < 4; ++r) {
            int c2 = wm * 64 + i * 16 + q * 4 + r;
            size_t ob = ((size_t)(n * 128 + c2) * 128 + h) * 128 + wn * 64 + lm;
            float sum = 0.0f, ssq = 0.0f;
#pragma unroll
            for (int j = 0; j < 4; ++j) {
                float v = acc[i][j][r];
                out[ob + j * 16] = v;
                sum += v; ssq += v * v;
            }
            // reduce over the 16 lanes sharing q (shifts stay within group)
#pragma unroll
            for (int d = 8; d > 0; d >>= 1) {
                sum += __shfl_down(sum, d);
                ssq += __shfl_down(ssq, d);
            }
            if (lm == 0) {
                // each P slot written exactly once per block (no atomics)
                P[wave * 64 + i * 16 + q * 4 + r] = make_float2(sum, ssq);
            }
        }
    }
    __syncthreads();
    // combine the wave pair sharing wm, write one partial row element
    {
        int stat = tid >> 7, c2x = tid & 127;      // row = stat*128+c2x == tid
        int wp = c2x >> 6, idx = c2x & 63;
        float2 a2 = P[(wp * 2) * 64 + idx];
        float2 b2 = P[(wp * 2 + 1) * 64 + idx];
        float val = stat ? (a2.y + b2.y) : (a2.x + b2.x);
        part[(size_t)tid * NBLK + bid] = val;
    }
}

// ---------------- K2b: reduce partials + finalize scale/shift ---------------
// 128 blocks, block c reduces part rows c (sum) and 128+c (ssq), each NBLK long.
__global__ __launch_bounds__(256) void reduce_stats(const float* __restrict__ part,
                                                    const float* __restrict__ gamma,
                                                    const float* __restrict__ beta,
                                                    float* __restrict__ ss) {
    int c = blockIdx.x;
    int tid = threadIdx.x;
    const float* ps = part + (size_t)c * NBLK;
    const float* pq = part + (size_t)(128 + c) * NBLK;
    float sum = 0.0f, ssq = 0.0f;
    for (int i = tid; i < NBLK; i += 256) { sum += ps[i]; ssq += pq[i]; }
#pragma unroll
    for (int d = 32; d > 0; d >>= 1) {
        sum += __shfl_down(sum, d);
        ssq += __shfl_down(ssq, d);
    }
    __shared__ float2 wred[4];
    if ((tid & 63) == 0) wred[tid >> 6] = make_float2(sum, ssq);
    __syncthreads();
    if (tid == 0) {
        float S = 0.0f, Q = 0.0f;
#pragma unroll
        for (int w2 = 0; w2 < 4; ++w2) { S += wred[w2].x; Q += wred[w2].y; }
        const float inv = 1.0f / NPIX;
        float mean = S * inv;
        float var = Q * inv - mean * mean;
        float sc = gamma[c] * rsqrtf(var + 1e-5f);
        ss[c] = sc;
        ss[128 + c] = beta[c] - mean * sc;
    }
}

// ---------------- K3: in-place BN apply (float4, grid-stride) ---------------
__global__ __launch_bounds__(256) void bn_apply(float* __restrict__ out,
                                                const float* __restrict__ ss) {
    const size_t stride = (size_t)2048 * 256;
    for (size_t i4 = (size_t)blockIdx.x * 256 + threadIdx.x; i4 < 16777216; i4 += stride) {
        int c2 = (int)((i4 >> 12) & 127);      // uniform within a block-iteration
        float sc = ss[c2], sh = ss[128 + c2];
        float4* p = (float4*)out + i4;
        float4 v = *p;
        v.x = v.x * sc + sh; v.y = v.y * sc + sh;
        v.z = v.z * sc + sh; v.w = v.w * sc + sh;
        *p = v;
    }
}

extern "C" void kernel_launch(void* const* d_in, const int* in_sizes, int n_in,
                              void* d_out, int out_size, void* d_ws, size_t ws_size,
                              hipStream_t stream) {
    const float* x     = (const float*)d_in[0];
    const float* cw    = (const float*)d_in[1];
    const float* gamma = (const float*)d_in[2];
    const float* beta  = (const float*)d_in[3];
    float* out = (float*)d_out;

    char* ws = (char*)d_ws;
    __bf16* s     = (__bf16*)ws;                           // 67108864 B
    __bf16* wfrag = (__bf16*)(ws + 67108864);              // 147456 B
    float*  part  = (float*)(ws + 67108864 + 147456);      // 256*NBLK*4 = 4 MB
    float*  ss    = part + 256 * NBLK;                     // 256 floats

    prep_w      <<<288,   256, 0, stream>>>(cw, wfrag);
    lif_kernel  <<<1024,  256, 0, stream>>>(x, s);
    conv_kernel <<<NBLK,  256, 0, stream>>>(s, wfrag, out, part);
    reduce_stats<<<128,   256, 0, stream>>>(part, gamma, beta, ss);
    bn_apply    <<<2048,  256, 0, stream>>>(out, ss);
}

// Round 4
// 519.343 us; speedup vs baseline: 1.2344x; 1.0369x over previous
//
#include <hip/hip_runtime.h>

typedef __bf16 bf16x8 __attribute__((ext_vector_type(8)));
typedef float f32x4 __attribute__((ext_vector_type(4)));

// Problem constants
// x: [T=4][B=8][C1=64][H=128][W=128] fp32
// conv_w: [C2=128][C1=64][3][3] fp32, gamma/beta: [128]
// out: [T][B][C2=128][H][W] fp32 == [n=T*B][c2][h][w]
#define TBCHW_PLANE 8388608      // B*C1*H*W = 8*64*128*128 (elems per t)
#define NPIX 524288.0f           // N*H*W = 32*128*128
#define NBLK 4096                // conv grid size (one block per (n,h))
#define SLOT_B 16640             // LDS row slot: 130 w_l positions * 64 c * 2 B

// ---------------- K0: weight repack to MFMA A-fragment order ----------------
// k ordering: k = tap*64 + c  (tap = kh*3+kw). Chunk kc (32 k's) => tap=kc>>1,
// c base=(kc&1)*32. Layout: wf[((kc*8+mtile)*64+lane)*8 + j], lane: m=lane&15,
// k_off=(lane>>4)*8+j  (A[m][k] per-lane fragment for mfma_f32_16x16x32_bf16).
__global__ __launch_bounds__(256) void prep_w(const float* __restrict__ w,
                                              __bf16* __restrict__ wf) {
    int o = blockIdx.x * 256 + threadIdx.x;
    if (o >= 73728) return;
    int j = o & 7;
    int lane = (o >> 3) & 63;
    int mtile = (o >> 9) & 7;
    int kc = o >> 12;
    int k = kc * 32 + (lane >> 4) * 8 + j;
    int c2 = mtile * 16 + (lane & 15);
    int tap = k >> 6, c = k & 63;
    int kh = tap / 3, kw = tap % 3;
    wf[o] = (__bf16)w[((c2 * 64 + c) * 3 + kh) * 3 + kw];
}

// ---------------- K1: LIF recurrence, fp32 exact, write s[n][h][w][c] bf16 ----
// LDS transpose layout: row stride 72 elems (144 B), c-position XOR-swizzled
// by ((w>>2)&7)<<3 to break the 32-way bank conflict of the 144B lane stride.
__device__ __forceinline__ float lif_step(float& mem, float sp, float xv) {
    // (mem - sp*0.5)*0.25 + xv : sp*0.5 and *0.25 are exact pow2 ops, so any
    // FMA contraction is bitwise-identical to the two-op IEEE sequence.
    mem = (mem - sp * 0.5f) * 0.25f + xv;
    return rintf(fminf(fmaxf(mem, 0.0f), 1.0f));   // round-half-even
}

__global__ __launch_bounds__(256) void lif_kernel(const float* __restrict__ x,
                                                  __bf16* __restrict__ s) {
    __shared__ __bf16 lds[2 * 128 * 72];  // [t2][w][c' 72] (144B row stride)
    int b = blockIdx.x >> 7, h = blockIdx.x & 127;
    int tid = threadIdx.x;

    float4 mem[8], sp[8];
#pragma unroll
    for (int i = 0; i < 8; ++i) { mem[i] = make_float4(0,0,0,0); sp[i] = make_float4(0,0,0,0); }

    for (int half = 0; half < 2; ++half) {
        if (half) __syncthreads();   // previous write-out done before LDS reuse
#pragma unroll
        for (int t2 = 0; t2 < 2; ++t2) {
            int t = half * 2 + t2;
#pragma unroll
            for (int i = 0; i < 8; ++i) {
                int p = tid + 256 * i;          // [0,2048): c=p>>5, w0=(p&31)*4
                int c = p >> 5, w0 = (p & 31) * 4;
                const float4 xv = *(const float4*)(x + (size_t)t * TBCHW_PLANE +
                                   (((size_t)b * 64 + c) * 128 + h) * 128 + w0);
                float s0 = lif_step(mem[i].x, sp[i].x, xv.x);
                float s1 = lif_step(mem[i].y, sp[i].y, xv.y);
                float s2 = lif_step(mem[i].z, sp[i].z, xv.z);
                float s3 = lif_step(mem[i].w, sp[i].w, xv.w);
                sp[i] = make_float4(s0, s1, s2, s3);
                // swizzled c position; (w0+k)>>2 == w0>>2 for k<4, so one base
                int cs = c ^ ((p & 7) << 3);    // (w0>>2)&7 == p&7
                __bf16* dst = &lds[(t2 * 128 + w0) * 72 + cs];
                dst[0] = (__bf16)s0; dst[72] = (__bf16)s1;
                dst[144] = (__bf16)s2; dst[216] = (__bf16)s3;
            }
        }
        __syncthreads();
        // write-out: contiguous 16B chunks over [w][c] per (t,h)
#pragma unroll
        for (int i = 0; i < 8; ++i) {
            int u = tid + 256 * i;              // [0,2048)
            int t2 = u >> 10, inner = u & 1023;
            int w = inner >> 3, c8 = inner & 7;
            int c8s = c8 ^ ((w >> 2) & 7);      // undo the store swizzle
            bf16x8 v = *(const bf16x8*)&lds[(t2 * 128 + w) * 72 + c8s * 8];
            int n = (half * 2 + t2) * 8 + b;
            *(bf16x8*)(s + (((size_t)n * 128 + h) * 128 + w) * 64 + c8 * 8) = v;
        }
    }
}

// ---------------- K2: implicit-GEMM conv (4096 blocks, swizzled LDS) --------
// Block = one (n, h): full C2=128 x W=128 tile. R2/R3-verified structure.
// R4 changes:
//  - conv output y written as bf16 (halves the y stream; stats still computed
//    from the fp32 accumulators, so mean/var are unchanged).
//  - part transposed to [bid][256] (contiguous 1 KB per block) to kill the
//    16x write-allocate amplification of the old [tid][bid] scatter.
__global__ __launch_bounds__(256, 3) void conv_kernel(const __bf16* __restrict__ s,
                                                      const __bf16* __restrict__ wf,
                                                      __bf16* __restrict__ y,
                                                      float* __restrict__ part) {
    __shared__ __align__(16) char sb3[3 * SLOT_B];   // 49920 B
    const int p = blockIdx.x;
    const int bid = (p & 7) * 512 + (p >> 3);        // bijective XCD-chunk map
    const int n = bid >> 7, h = bid & 127;
    const int tid = threadIdx.x;

    // stage rows h-1..h+1 into slots kh=0..2 (each 128w x 64c bf16, 16 KB)
#pragma unroll
    for (int r = 0; r < 3; ++r) {
        int hh = h + r - 1;
        char* slot = sb3 + r * SLOT_B;
        if (hh >= 0 && hh < 128) {
            const char* src = (const char*)s + (((size_t)n * 128 + hh) << 14);
#pragma unroll
            for (int i = 0; i < 4; ++i) {
                int g = i * 256 + tid;               // granule [0,1024): w=g>>3
                int w = g >> 3;
                int sg = (w << 7) + (((g & 7) ^ ((w + 1) & 7)) << 4);  // inv-swizzled src
                __builtin_amdgcn_global_load_lds(
                    (const __attribute__((address_space(1))) unsigned int*)(src + sg),
                    (__attribute__((address_space(3))) unsigned int*)(slot + 128 + g * 16),
                    16, 0, 0);
            }
        } else {
            f32x4 z = {0.f, 0.f, 0.f, 0.f};
#pragma unroll
            for (int i = 0; i < 4; ++i)
                *(f32x4*)(slot + 128 + (i * 256 + tid) * 16) = z;
        }
    }
    if (tid < 48) {   // zero halo columns w_l=0 and w_l=129 of the 3 slots
        int r = tid / 16, q16 = tid % 16;
        int col = q16 & 1, g8 = q16 >> 1;
        f32x4 z = {0.f, 0.f, 0.f, 0.f};
        *(f32x4*)(sb3 + r * SLOT_B + (col ? 129 * 128 : 0) + g8 * 16) = z;
    }

    const int lane = tid & 63, wave = tid >> 6;
    const int wm = wave >> 1, wn = wave & 1;    // 2x2 wave grid, 64x64 each
    const int lm = lane & 15, q = lane >> 4;
    const int wbyte = (wn * 64 + lm) * 128;     // w_l byte base (j adds 2048)

    // preload kc=0 A-fragments while the staging loads are in flight
    bf16x8 aC[4], aN[4];
#pragma unroll
    for (int i = 0; i < 4; ++i)
        aC[i] = *(const bf16x8*)(wf + (((size_t)wm * 4 + i) * 64 + lane) * 8);

    __syncthreads();   // drains vmcnt (gload_lds) + lgkm (halo zeros)

    f32x4 acc[4][4];
#pragma unroll
    for (int i = 0; i < 4; ++i)
#pragma unroll
        for (int j = 0; j < 4; ++j)
#pragma unroll
            for (int e = 0; e < 4; ++e) acc[i][j][e] = 0.0f;

#pragma unroll
    for (int kc = 0; kc < 18; ++kc) {
        const int tap = kc >> 1;
        const int kh = tap / 3, kw = tap - kh * 3;   // compile-time (unrolled)
        const int c8b = (kc & 1) * 4;
        const char* rb = sb3 + kh * SLOT_B;
        // swizzle is j/wn-independent: (w_l & 7) == (lm + kw) & 7
        const int off = kw * 128 + (((c8b + q) ^ ((lm + kw) & 7)) << 4);
        // software-pipelined A: issue kc+1's loads before kc's MFMAs
        if (kc < 17) {
#pragma unroll
            for (int i = 0; i < 4; ++i)
                aN[i] = *(const bf16x8*)(wf + (((size_t)(kc + 1) * 8 + wm * 4 + i) * 64 + lane) * 8);
        }
        bf16x8 bb[4];
#pragma unroll
        for (int j = 0; j < 4; ++j)
            bb[j] = *(const bf16x8*)(rb + wbyte + j * 2048 + off);
#pragma unroll
        for (int i = 0; i < 4; ++i)
#pragma unroll
            for (int j = 0; j < 4; ++j)
                acc[i][j] = __builtin_amdgcn_mfma_f32_16x16x32_bf16(aC[i], bb[j], acc[i][j], 0, 0, 0);
#pragma unroll
        for (int i = 0; i < 4; ++i) aC[i] = aN[i];   // renamed away by unroll
    }

    __syncthreads();                       // done reading sb3; reuse as float2 P
    float2* P = (float2*)sb3;              // P[wave*64 + idx], idx = i*16+q*4+r

    // epilogue: D[m = q*4+r][nn = lane&15]; store bf16 y + per-channel partials
    // (stats from fp32 accumulators -> mean/var unchanged by y quantization;
    //  scalar 2B stores: the 4 j-stores of a wave fill whole 64B lines, L2
    //  merges them before eviction)
#pragma unroll
    for (int i = 0; i < 4; ++i) {
#pragma unroll
        for (int r = 0; r < 4; ++r) {
            int c2 = wm * 64 + i * 16 + q * 4 + r;
            size_t ob = ((size_t)(n * 128 + c2) * 128 + h) * 128 + wn * 64 + lm;
            float sum = 0.0f, ssq = 0.0f;
#pragma unroll
            for (int j = 0; j < 4; ++j) {
                float v = acc[i][j][r];
                y[ob + j * 16] = (__bf16)v;
                sum += v; ssq += v * v;
            }
            // reduce over the 16 lanes sharing q (shifts stay within group)
#pragma unroll
            for (int d = 8; d > 0; d >>= 1) {
                sum += __shfl_down(sum, d);
                ssq += __shfl_down(ssq, d);
            }
            if (lm == 0) {
                // each P slot written exactly once per block (no atomics)
                P[wave * 64 + i * 16 + q * 4 + r] = make_float2(sum, ssq);
            }
        }
    }
    __syncthreads();
    // combine the wave pair sharing wm; row-contiguous part write (1 KB/block)
    {
        int c2x = tid & 127;                       // col = tid: <128 sum, >=128 ssq
        int wp = c2x >> 6, idx = c2x & 63;
        float2 a2 = P[(wp * 2) * 64 + idx];
        float2 b2 = P[(wp * 2 + 1) * 64 + idx];
        float val = (tid >> 7) ? (a2.y + b2.y) : (a2.x + b2.x);
        part[(size_t)bid * 256 + tid] = val;
    }
}

// ---------------- K2b: 2-stage coalesced stat reduction ---------------------
// stage1: 64 blocks, block b sums 64 part rows (each row 256 floats, coalesced)
__global__ __launch_bounds__(256) void reduce_stage1(const float* __restrict__ part,
                                                     float* __restrict__ part2) {
    int tid = threadIdx.x;
    float acc = 0.0f;
    const float* base = part + (size_t)blockIdx.x * 64 * 256;
#pragma unroll 8
    for (int r = 0; r < 64; ++r) acc += base[r * 256 + tid];
    part2[blockIdx.x * 256 + tid] = acc;
}

// stage2: 1 block reduces 64x256 -> scale/shift
__global__ __launch_bounds__(256) void reduce_stage2(const float* __restrict__ part2,
                                                     const float* __restrict__ gamma,
                                                     const float* __restrict__ beta,
                                                     float* __restrict__ ss) {
    int tid = threadIdx.x;
    float tot = 0.0f;
#pragma unroll 8
    for (int b = 0; b < 64; ++b) tot += part2[b * 256 + tid];
    __shared__ float T[256];
    T[tid] = tot;
    __syncthreads();
    if (tid < 128) {
        const float inv = 1.0f / NPIX;
        float mean = T[tid] * inv;
        float var = T[128 + tid] * inv - mean * mean;
        float sc = gamma[tid] * rsqrtf(var + 1e-5f);
        ss[tid] = sc;
        ss[128 + tid] = beta[tid] - mean * sc;
    }
}

// ---------------- K3: BN apply, bf16 y -> fp32 out (grid-stride) ------------
__global__ __launch_bounds__(256) void bn_apply(const __bf16* __restrict__ y,
                                                float* __restrict__ out,
                                                const float* __restrict__ ss) {
    const size_t stride = (size_t)2048 * 256;
    for (size_t i8 = (size_t)blockIdx.x * 256 + threadIdx.x; i8 < 8388608; i8 += stride) {
        int c2 = (int)((i8 >> 11) & 127);      // uniform within a block-iteration
        float sc = ss[c2], sh = ss[128 + c2];
        bf16x8 v = *(const bf16x8*)(y + i8 * 8);
        f32x4 o0, o1;
#pragma unroll
        for (int e = 0; e < 4; ++e) {
            o0[e] = (float)v[e] * sc + sh;
            o1[e] = (float)v[4 + e] * sc + sh;
        }
        f32x4* dst = (f32x4*)out + i8 * 2;
        dst[0] = o0;
        dst[1] = o1;
    }
}

extern "C" void kernel_launch(void* const* d_in, const int* in_sizes, int n_in,
                              void* d_out, int out_size, void* d_ws, size_t ws_size,
                              hipStream_t stream) {
    const float* x     = (const float*)d_in[0];
    const float* cw    = (const float*)d_in[1];
    const float* gamma = (const float*)d_in[2];
    const float* beta  = (const float*)d_in[3];
    float* out = (float*)d_out;

    char* ws = (char*)d_ws;
    __bf16* s     = (__bf16*)ws;                           // 67108864 B
    __bf16* y     = (__bf16*)(ws + 67108864);              // 134217728 B
    __bf16* wfrag = (__bf16*)(ws + 201326592);             // 147456 B
    float*  part  = (float*)(ws + 201474048);              // 4096*256*4 = 4 MB
    float*  part2 = (float*)(ws + 205668352);              // 64*256*4 = 64 KB
    float*  ss    = (float*)(ws + 205733888);              // 256 floats

    prep_w       <<<288,   256, 0, stream>>>(cw, wfrag);
    lif_kernel   <<<1024,  256, 0, stream>>>(x, s);
    conv_kernel  <<<NBLK,  256, 0, stream>>>(s, wfrag, y, part);
    reduce_stage1<<<64,    256, 0, stream>>>(part, part2);
    reduce_stage2<<<1,     256, 0, stream>>>(part2, gamma, beta, ss);
    bn_apply     <<<2048,  256, 0, stream>>>(y, out, ss);
}